// Round 7
// baseline (181.962 us; speedup 1.0000x reference)
//
#include <hip/hip_runtime.h>
#include <hip/hip_bf16.h>

// LSTM cell fused kernel for MI355X (gfx950) — round 7: LDS-FREE GEMM.
// Both operands pre-converted to per-wave fragment-ordered layouts; the GEMM
// streams fragments global->VGPR with counted vmcnt (per-wave scoreboard),
// 32 MFMA per half-K step, no ds_read/ds_write, 1 barrier/K-tile (L1
// phase-lock only — carries no data dependency).
//
// stacked = [x|prevh] @ [Wx;Wh] + bx -> gates -> nexth, nextc
// GEMM: M=8192, N=4096 (4 gates x 1024 states), K=2048, bf16 16x16x32 MFMA.
//
// Af layout (convA2): chunk (mw=mt*2+wr, kt) = 16 KB = [m:8][kf:2][lane:64][e:8],
//   elem = A[mt*256+wr*128+m*16+(lane&15)][kt*64+kf*32+(lane>>4)*8+e]
// Wt2 layout (convW2, verified r6): chunk (nt*4+wc, kt) = 8 KB =
//   [g:4][kf:2][lane:64][e:8], elem = W[k][g*1024+nt*64+wc*16+(lane&15)]
//
// K-loop: 64 half-K steps (K=32). Steady state: LOADF(next) issued before
// MFMA(cur); vmcnt(12) with 24 outstanding waits exactly for cur's 12 loads
// (m135: waits oldest (outstanding-N)). Never drains mid-loop.
//
// ws: Af bf16 [8192][2048] frag-ordered (32MB) | Wt2 frag-ordered (16MB)

#define BATCH   8192
#define SDIM    1024
#define KDIM    2048
#define NHS     64      // half-K steps of 32

typedef __attribute__((ext_vector_type(8))) short s16x8;
typedef __attribute__((ext_vector_type(4))) float f32x4;

__device__ __forceinline__ float fast_sigmoid(float x) {
    return 1.0f / (1.0f + __expf(-x));
}
__device__ __forceinline__ float fast_tanh(float v) {
    float a = fabsf(v);
    float e = __expf(-2.0f * a);
    float t = (1.0f - e) / (1.0f + e);
    return copysignf(t, v);
}

// ---- conversion to fragment-ordered Af (LDS-tiled for coalescing) ----------
// One block per (mw, kt) chunk: reads fp32 rows coalesced, emits 16 KB chunk.
__global__ void convA2(const float* __restrict__ x, const float* __restrict__ h,
                       __hip_bfloat16* __restrict__ Af) {
    __shared__ float tile[128][68];   // pad 64->68: frag-read ~2-way (free)
    const int blk = blockIdx.x;       // (mw)*32 + kt, mw = mt*2+wr
    const int kt  = blk & 31;
    const int mw  = blk >> 5;         // 0..63
    const int row0 = mw * 128;
    const int k0   = kt * 64;         // 64-aligned: never straddles x/h split
    const int t = threadIdx.x;        // 0..255

    const int r  = t >> 1;            // 0..127
    const int kc = (t & 1) * 32;
    const float* src = (k0 < 1024)
        ? (x + (size_t)(row0 + r) * 1024 + k0 + kc)
        : (h + (size_t)(row0 + r) * 1024 + (k0 - 1024) + kc);
#pragma unroll
    for (int j = 0; j < 8; ++j)
        *(float4*)&tile[r][kc + j * 4] = *(const float4*)(src + j * 4);
    __syncthreads();

#pragma unroll
    for (int q = 0; q < 4; ++q) {
        int w    = t + q * 256;       // 16B-word index in chunk, 0..1023
        int lane = w & 63;
        int kf   = (w >> 6) & 1;
        int m    = w >> 7;
        int rr   = m * 16 + (lane & 15);
        int cc   = kf * 32 + (lane >> 4) * 8;
        union { __hip_bfloat16 b[8]; s16x8 v; } u;
#pragma unroll
        for (int e = 0; e < 8; ++e)
            u.b[e] = __float2bfloat16(tile[rr][cc + e]);
        *(s16x8*)(Af + ((size_t)blk * 1024 + w) * 8) = u.v;
    }
}

// ---- conversion to fragment-ordered Wt2 (verified round 6) -----------------
__global__ void convW2(const float* __restrict__ Wx, const float* __restrict__ Wh,
                       __hip_bfloat16* __restrict__ Wt2) {
    int tid  = blockIdx.x * blockDim.x + threadIdx.x;   // 1,048,576
    int lane = tid & 63;
    int r    = tid >> 6;
    int kfg  = r & 7;          // g*2+kf
    int g    = kfg >> 1;
    int kf   = kfg & 1;
    int r2   = r >> 3;
    int kt   = r2 & 31;
    int r3   = r2 >> 5;
    int wc   = r3 & 3;
    int ntl  = r3 >> 2;        // 0..15
    int n     = g * 1024 + ntl * 64 + wc * 16 + (lane & 15);
    int kbase = kt * 64 + kf * 32 + (lane >> 4) * 8;
    const float* src = (kbase < 1024) ? (Wx + (size_t)kbase * 4096 + n)
                                      : (Wh + (size_t)(kbase - 1024) * 4096 + n);
    union { __hip_bfloat16 b[8]; s16x8 v; } u;
#pragma unroll
    for (int e = 0; e < 8; ++e)
        u.b[e] = __float2bfloat16(src[(size_t)e * 4096]);
    *(s16x8*)((char*)Wt2 + (size_t)tid * 16) = u.v;
}

// ---------------- fused GEMM + gates (no LDS) -------------------------------
__global__ __launch_bounds__(512, 2) void lstm_gemm(
    const __hip_bfloat16* __restrict__ Af,   // frag-ordered (32MB)
    const __hip_bfloat16* __restrict__ Wt2,  // frag-ordered (16MB)
    const float* __restrict__ bx,            // [4096]
    const float* __restrict__ prevc,         // [8192][1024]
    float* __restrict__ outh,
    float* __restrict__ outc)
{
    const int tid  = threadIdx.x;
    const int lane = tid & 63;
    const int w    = tid >> 6;   // 0..7
    const int wr   = w >> 2;     // 0..1
    const int wc   = w & 3;      // 0..3
    const int l15  = lane & 15;

    // XCD chunking (FETCH-verified r3-r6): 8 chunks of 8Mt x 8Nt.
    const int bid = blockIdx.x;
    const int xcd = bid & 7, jj = bid >> 3;
    const int mt = (xcd >> 1) * 8 + (jj & 7);     // 0..31
    const int nt = (xcd & 1) * 8 + (jj >> 3);     // 0..15
    const int m0 = mt * 256, S0 = nt * 64;

    // per-wave fragment streams (contiguous: A 512KB, B 256KB)
    const char* pA = (const char*)Af
                   + ((size_t)(mt * 2 + wr) * 32) * 16384 + (size_t)lane * 16;
    const char* pB = (const char*)Wt2
                   + ((size_t)(nt * 4 + wc) * 32) * 8192 + (size_t)lane * 16;

    f32x4 acc[8][4];
#pragma unroll
    for (int m = 0; m < 8; ++m)
#pragma unroll
        for (int g = 0; g < 4; ++g)
            acc[m][g] = (f32x4)0.0f;

    s16x8 aX[8], bX[4], aY[8], bY[4];

#define LOADF(AR, BR, S)                                                      \
    {                                                                         \
        const char* a_ = pA + (size_t)((S) >> 1) * 16384 + ((S) & 1) * 1024;  \
        const char* b_ = pB + (size_t)((S) >> 1) * 8192 + ((S) & 1) * 1024;   \
        _Pragma("unroll")                                                     \
        for (int m = 0; m < 8; ++m)                                           \
            AR[m] = *(const s16x8*)(a_ + m * 2048);                           \
        _Pragma("unroll")                                                     \
        for (int g = 0; g < 4; ++g)                                           \
            BR[g] = *(const s16x8*)(b_ + g * 2048);                           \
    }

#define MF(AR, BR)                                                            \
    __builtin_amdgcn_s_setprio(1);                                            \
    _Pragma("unroll")                                                         \
    for (int m = 0; m < 8; ++m)                                               \
        _Pragma("unroll")                                                     \
        for (int g = 0; g < 4; ++g)                                           \
            acc[m][g] = __builtin_amdgcn_mfma_f32_16x16x32_bf16(              \
                AR[m], BR[g], acc[m][g], 0, 0, 0);                            \
    __builtin_amdgcn_s_setprio(0);

    LOADF(aX, bX, 0);
    for (int s = 0; s < NHS; s += 2) {
        LOADF(aY, bY, s + 1);                      // outstanding: X(12)+Y(12)
        asm volatile("s_waitcnt vmcnt(12)" ::: "memory");   // X complete
        __builtin_amdgcn_sched_barrier(0);
        MF(aX, bX);

        if (s + 2 < NHS) {
            LOADF(aX, bX, s + 2);                  // outstanding: Y(12)+X'(12)
            asm volatile("s_waitcnt vmcnt(12)" ::: "memory");   // Y complete
        } else {
            asm volatile("s_waitcnt vmcnt(0)" ::: "memory");
        }
        __builtin_amdgcn_sched_barrier(0);
        MF(aY, bY);

        // phase-lock the block's waves (L1 dedup of shared A/B streams).
        // No data dependency rides on this barrier.
        __builtin_amdgcn_s_barrier();
    }
#undef LOADF
#undef MF

    // ---- fused epilogue: 4 gates lane-local ----
    const int st  = S0 + wc * 16 + l15;
    const float b_i = bx[st];
    const float b_f = bx[1024 + st];
    const float b_o = bx[2048 + st];
    const float b_g = bx[3072 + st];
    const int rbase = m0 + wr * 128 + (lane >> 4) * 4;

#pragma unroll
    for (int m = 0; m < 8; ++m) {
#pragma unroll
        for (int q = 0; q < 4; ++q) {
            int row = rbase + m * 16 + q;
            float ib = acc[m][0][q] + b_i;
            float fb = acc[m][1][q] + b_f;
            float ob = acc[m][2][q] + b_o;
            float gb = acc[m][3][q] + b_g;
            float ig = fast_sigmoid(ib);
            float fg = fast_sigmoid(fb);
            float og = fast_sigmoid(ob);
            float gg = fast_tanh(gb);
            float pc = prevc[(size_t)row * SDIM + st];
            float nc = pc * fg + gg * ig;
            float nh = fast_tanh(nc) * og;
            outh[(size_t)row * SDIM + st] = nh;
            outc[(size_t)row * SDIM + st] = nc;
        }
    }
}

extern "C" void kernel_launch(void* const* d_in, const int* in_sizes, int n_in,
                              void* d_out, int out_size, void* d_ws, size_t ws_size,
                              hipStream_t stream) {
    const float* x     = (const float*)d_in[0];
    const float* prevh = (const float*)d_in[1];
    const float* prevc = (const float*)d_in[2];
    const float* Wx    = (const float*)d_in[3];
    const float* bx    = (const float*)d_in[4];
    const float* Wh    = (const float*)d_in[5];

    __hip_bfloat16* Afr = (__hip_bfloat16*)d_ws;
    __hip_bfloat16* Wt2 = Afr + (size_t)BATCH * KDIM;   // +32MB

    float* outh = (float*)d_out;
    float* outc = outh + (size_t)BATCH * SDIM;

    // A fragment conversion: 64 mw-halves x 32 k-tiles
    hipLaunchKernelGGL(convA2, dim3(2048), dim3(256), 0, stream, x, prevh, Afr);
    hipLaunchKernelGGL(convW2, dim3(4096), dim3(256), 0, stream, Wx, Wh, Wt2);
    hipLaunchKernelGGL(lstm_gemm, dim3(512), dim3(512), 0, stream,
                       Afr, Wt2, bx, prevc, outh, outc);
}

// Round 8
// 172.246 us; speedup vs baseline: 1.0564x; 1.0564x over previous
//
#include <hip/hip_runtime.h>
#include <hip/hip_bf16.h>

// LSTM cell fused kernel for MI355X (gfx950) — round 8: 32x32x16 MFMA.
// stacked = [x|prevh] @ [Wx;Wh] + bx -> gates -> nexth, nextc
// GEMM: M=8192, N=4096 (4 gates x 1024 states), K=2048, bf16 32x32x16 MFMA
// (2495 TF ceiling vs 2176 for 16x16; half the MFMA instructions).
//
// Structure (r5/r6-equivalent schedule, shape swapped):
//   256x256 tile, BK=64, 8 waves as 4M x 2N; per-wave 64 rows x 128 n'-cols
//   (= 4 gates x 32 states). LDS 128 KiB: A dbuf 2x32KB, B dbuf 2x32KB,
//   slot = t&1. Per tile: top stages A(t+1)+B(t+1) (8 gloads, full-tile
//   latency cover); 4 ks-chunks x 6 ds_read_b128 pipelined one-ahead with
//   lgkm(6); 4 MFMA blocks of 8 (acc[mt][g], 8 indep chains); end vmcnt(0)
//   [cheap: everything outstanding issued a full tile ago] + ONE barrier.
//   WAR: SA(t+1) overwrites slot of A(t-1), fully read before end-bar(t-1).
//
// Fragment maps (32x32x16): A lane: row=l&31, k=(l>>5)*8+e. B lane:
// col=l&31, k=(l>>5)*8+e. C/D: col=l&31, row=(reg&3)+8*(reg>>2)+4*(l>>5)
// [measured m74/m101].
//
// T2 swizzle (verified 0 conflicts r3-r6): granule' = g ^ (row&7), both
// sides (inverse-swizzled gload source + swizzled ds_read). For 32-row
// fragment reads: 64 lanes spread uniformly over all 8 granules (32 B/bank)
// -> conflict-free.
//
// Gate fusion: Wt permuted n' = (s>>5)*128 + gate*32 + (s&31); each wave's
// 128 n'-cols = 4 gates x 32 states -> all 4 gates lane-local in epilogue.
//
// ws: A_bf16 [8192][2048] (32MB) | Wt bf16 [4096 perm][2048] (16MB)

#define BATCH   8192
#define SDIM    1024
#define KDIM    2048
#define NT      32      // K-tiles of 64

typedef __attribute__((ext_vector_type(8)))  short s16x8;
typedef __attribute__((ext_vector_type(16))) float f32x16;

__device__ __forceinline__ void gload16(const void* g, void* l) {
    __builtin_amdgcn_global_load_lds((const __attribute__((address_space(1))) void*)g,
                                     (__attribute__((address_space(3))) void*)l,
                                     16, 0, 0);
}

__device__ __forceinline__ float fast_sigmoid(float x) {
    return 1.0f / (1.0f + __expf(-x));
}
__device__ __forceinline__ float fast_tanh(float v) {
    float a = fabsf(v);
    float e = __expf(-2.0f * a);
    float t = (1.0f - e) / (1.0f + e);
    return copysignf(t, v);
}

// ---------------- conversion: A = [x | prevh] -> bf16 [8192][2048] ----------
__global__ void convA(const float* __restrict__ x, const float* __restrict__ h,
                      __hip_bfloat16* __restrict__ A) {
    int t = blockIdx.x * blockDim.x + threadIdx.x;
    int e = t << 3;
    int b = e >> 11;
    int k = e & 2047;
    const float* src = (k < 1024) ? (x + (size_t)b * 1024 + k)
                                  : (h + (size_t)b * 1024 + (k - 1024));
    float4 v0 = *(const float4*)(src);
    float4 v1 = *(const float4*)(src + 4);
    union { __hip_bfloat16 b[8]; s16x8 v; } u;
    u.b[0] = __float2bfloat16(v0.x); u.b[1] = __float2bfloat16(v0.y);
    u.b[2] = __float2bfloat16(v0.z); u.b[3] = __float2bfloat16(v0.w);
    u.b[4] = __float2bfloat16(v1.x); u.b[5] = __float2bfloat16(v1.y);
    u.b[6] = __float2bfloat16(v1.z); u.b[7] = __float2bfloat16(v1.w);
    *(s16x8*)(A + e) = u.v;
}

// ---- conversion + transpose + gate-permute: Wt[n'][k] = W[k][n] -----------
// n = gate*1024 + s  ->  n' = (s>>5)*128 + gate*32 + (s&31)
__global__ void convW(const float* __restrict__ Wx, const float* __restrict__ Wh,
                      __hip_bfloat16* __restrict__ Wt) {
    __shared__ float tile[32][33];
    int k0 = blockIdx.x * 32;
    int n0 = blockIdx.y * 32;
    int tx = threadIdx.x;
    int ty = threadIdx.y;
#pragma unroll
    for (int j = 0; j < 4; ++j) {
        int k = k0 + ty + j * 8;
        int n = n0 + tx;
        float v = (k < 1024) ? Wx[(size_t)k * 4096 + n]
                             : Wh[(size_t)(k - 1024) * 4096 + n];
        tile[ty + j * 8][tx] = v;
    }
    __syncthreads();
#pragma unroll
    for (int j = 0; j < 4; ++j) {
        int n = n0 + ty + j * 8;
        int k = k0 + tx;
        int np = ((n & 1023) >> 5) * 128 + (n >> 10) * 32 + (n & 31);
        Wt[(size_t)np * 2048 + k] = __float2bfloat16(tile[tx][ty + j * 8]);
    }
}

// ---------------- fused GEMM + gates ----------------------------------------
__global__ __launch_bounds__(512, 2) void lstm_gemm(
    const __hip_bfloat16* __restrict__ A,    // [8192][2048]
    const __hip_bfloat16* __restrict__ Wt,   // [4096 perm][2048]
    const float* __restrict__ bx,            // [4096]
    const float* __restrict__ prevc,         // [8192][1024]
    float* __restrict__ outh,
    float* __restrict__ outc)
{
    // A: slots 0/1 at [0,64K); B: slots at [64K,128K). Slot = 32 KB.
    __shared__ __align__(16) char lds[131072];

    const int tid  = threadIdx.x;
    const int lane = tid & 63;
    const int w    = tid >> 6;   // 0..7
    const int wv   = w >> 1;     // 0..3  M quarter (64 rows)
    const int wc   = w & 1;      // 0..1  N half (128 n'-cols)
    const int l31  = lane & 31;

    // XCD chunking (FETCH-verified): 8 chunks of 8Mt x 8Nt.
    const int bid = blockIdx.x;
    const int xcd = bid & 7, jj = bid >> 3;
    const int mt = (xcd >> 1) * 8 + (jj & 7);     // 0..31
    const int nt = (xcd & 1) * 8 + (jj >> 3);     // 0..15
    const int m0 = mt * 256, n0 = nt * 256;

    // staging: linear gload_lds dest, inverse-swizzled global source.
    const int scol = ((lane & 7) ^ (lane >> 3)) << 3;   // elems
    const __hip_bfloat16* Ag = A  + (size_t)m0 * KDIM;
    const __hip_bfloat16* Bg = Wt + (size_t)n0 * KDIM;

    auto SA = [&](int tt) {
        char* dst = lds + (tt & 1) * 32768 + w * 1024;
        const __hip_bfloat16* src =
            Ag + (size_t)(w * 8 + (lane >> 3)) * KDIM + tt * 64 + scol;
#pragma unroll
        for (int r = 0; r < 4; ++r)
            gload16(src + (size_t)(r * 64) * KDIM, dst + r * 8192);
    };
    auto SB = [&](int tt) {
        char* dst = lds + 65536 + (tt & 1) * 32768 + w * 1024;
        const __hip_bfloat16* src =
            Bg + (size_t)(w * 8 + (lane >> 3)) * KDIM + tt * 64 + scol;
#pragma unroll
        for (int r = 0; r < 4; ++r)
            gload16(src + (size_t)(r * 64) * KDIM, dst + r * 8192);
    };

    f32x16 acc[2][4];   // [m_tile][gate]
#pragma unroll
    for (int m = 0; m < 2; ++m)
#pragma unroll
        for (int g = 0; g < 4; ++g)
            acc[m][g] = (f32x16)0.0f;

    // prologue
    SA(0); SB(0);
    asm volatile("s_waitcnt vmcnt(0)" ::: "memory");
    __builtin_amdgcn_s_barrier();
    __builtin_amdgcn_sched_barrier(0);

    // read-side swizzle per ks: granule = (ks*2 + (lane>>5)) ^ (lane&7)
    int swzk[4];
#pragma unroll
    for (int ks = 0; ks < 4; ++ks)
        swzk[ks] = (((ks * 2 + (lane >> 5)) ^ (lane & 7)) << 4);
    const int arow = (wv * 64 + l31) * 128;    // + mt*32*128
    const int brow = (wc * 128 + l31) * 128;   // + g*32*128

    s16x8 aP[2], bP[4], aQ[2], bQ[4];

#define LGKM(n)                                             \
    asm volatile("s_waitcnt lgkmcnt(" #n ")" ::: "memory"); \
    __builtin_amdgcn_sched_barrier(0);

#define RDC(AF, BF, KS)                                                       \
    _Pragma("unroll")                                                         \
    for (int m = 0; m < 2; ++m)                                               \
        AF[m] = *(const s16x8*)(as + arow + m * 4096 + swzk[KS]);             \
    _Pragma("unroll")                                                         \
    for (int g = 0; g < 4; ++g)                                               \
        BF[g] = *(const s16x8*)(bs + brow + g * 4096 + swzk[KS]);

#define MC(AF, BF)                                                            \
    __builtin_amdgcn_s_setprio(1);                                            \
    _Pragma("unroll")                                                         \
    for (int m = 0; m < 2; ++m)                                               \
        _Pragma("unroll")                                                     \
        for (int g = 0; g < 4; ++g)                                           \
            acc[m][g] = __builtin_amdgcn_mfma_f32_32x32x16_bf16(              \
                AF[m], BF[g], acc[m][g], 0, 0, 0);                            \
    __builtin_amdgcn_s_setprio(0);

    for (int t = 0; t < NT; ++t) {
        const char* as = lds + (t & 1) * 32768;
        const char* bs = lds + 65536 + (t & 1) * 32768;

        if (t + 1 < NT) { SA(t + 1); SB(t + 1); }   // 8 gloads, land by end-bar

        RDC(aP, bP, 0);
        RDC(aQ, bQ, 1);
        LGKM(6);  MC(aP, bP);          // ks0 (C1 drains under it)
        RDC(aP, bP, 2);
        LGKM(6);  MC(aQ, bQ);          // ks1
        RDC(aQ, bQ, 3);
        LGKM(6);  MC(aP, bP);          // ks2
        LGKM(0);  MC(aQ, bQ);          // ks3

        // staged loads issued a full tile ago -> drain is free
        asm volatile("s_waitcnt vmcnt(0)" ::: "memory");
        __builtin_amdgcn_s_barrier();
        __builtin_amdgcn_sched_barrier(0);
    }
#undef RDC
#undef MC
#undef LGKM

    // ---- fused epilogue: 4 gates lane-local (32x32 C-map) ----
    const int st  = (nt * 2 + wc) * 32 + l31;   // state column
    const float b_i = bx[st];
    const float b_f = bx[1024 + st];
    const float b_o = bx[2048 + st];
    const float b_g = bx[3072 + st];
    const int rbase = m0 + wv * 64 + ((lane >> 5) << 2);

#pragma unroll
    for (int m = 0; m < 2; ++m) {
#pragma unroll
        for (int reg = 0; reg < 16; ++reg) {
            int row = rbase + m * 32 + (reg & 3) + ((reg >> 2) << 3);
            float ib = acc[m][0][reg] + b_i;
            float fb = acc[m][1][reg] + b_f;
            float ob = acc[m][2][reg] + b_o;
            float gb = acc[m][3][reg] + b_g;
            float ig = fast_sigmoid(ib);
            float fg = fast_sigmoid(fb);
            float og = fast_sigmoid(ob);
            float gg = fast_tanh(gb);
            float pc = prevc[(size_t)row * SDIM + st];
            float nc = pc * fg + gg * ig;
            float nh = fast_tanh(nc) * og;
            outh[(size_t)row * SDIM + st] = nh;
            outc[(size_t)row * SDIM + st] = nc;
        }
    }
}

extern "C" void kernel_launch(void* const* d_in, const int* in_sizes, int n_in,
                              void* d_out, int out_size, void* d_ws, size_t ws_size,
                              hipStream_t stream) {
    const float* x     = (const float*)d_in[0];
    const float* prevh = (const float*)d_in[1];
    const float* prevc = (const float*)d_in[2];
    const float* Wx    = (const float*)d_in[3];
    const float* bx    = (const float*)d_in[4];
    const float* Wh    = (const float*)d_in[5];

    __hip_bfloat16* Abf = (__hip_bfloat16*)d_ws;
    __hip_bfloat16* Wt  = Abf + (size_t)BATCH * KDIM;   // +32MB

    float* outh = (float*)d_out;
    float* outc = outh + (size_t)BATCH * SDIM;

    hipLaunchKernelGGL(convA, dim3(8192), dim3(256), 0, stream, x, prevh, Abf);
    hipLaunchKernelGGL(convW, dim3(64, 128), dim3(32, 8), 0, stream, Wx, Wh, Wt);
    hipLaunchKernelGGL(lstm_gemm, dim3(512), dim3(512), 0, stream,
                       Abf, Wt, bx, prevc, outh, outc);
}